// Round 12
// baseline (3284.718 us; speedup 1.0000x reference)
//
#include <hip/hip_runtime.h>
#include <stdint.h>

#define D 1024

typedef unsigned long long u64;
typedef unsigned int u32;

// ---------- monotonic float<->uint mapping for atomic max ----------
__device__ __forceinline__ u32 enc_f(float f) {
    u32 b = __float_as_uint(f);
    return (b & 0x80000000u) ? ~b : (b | 0x80000000u);
}
__device__ __forceinline__ float dec_f(u32 u) {
    u32 b = (u & 0x80000000u) ? (u ^ 0x80000000u) : ~u;
    return __uint_as_float(b);
}

// LDS-only barrier: synchronizes DS traffic but does NOT drain vmcnt.
// Used at B2 only: the sole pending global store there is the coalesced
// row-m1 store, which has NO consumer inside P3 (rescans substitute col m1
// from LDS and never read row m1; wave0/wave1 scan LDS only; speculative
// loads substitute rows/col m1 from LDS history). It drains in the shadow
// of P3 and is retired by the full __syncthreads() at B3.
__device__ __forceinline__ void barrier_lds_only() {
    __builtin_amdgcn_sched_barrier(0);
    asm volatile("s_waitcnt lgkmcnt(0)" ::: "memory");
    __builtin_amdgcn_s_barrier();
    asm volatile("" ::: "memory");
    __builtin_amdgcn_sched_barrier(0);
}

// ---------- kernel A: max(X), max|X| ----------
__global__ void k_maxred(const float* __restrict__ X, u32* scal) {
    float mx = -INFINITY, ma = 0.f;
    int stride = gridDim.x * blockDim.x;
    for (int i = blockIdx.x * blockDim.x + threadIdx.x; i < D * D; i += stride) {
        float v = X[i];
        mx = fmaxf(mx, v);
        ma = fmaxf(ma, fabsf(v));
    }
    for (int o = 32; o; o >>= 1) {
        mx = fmaxf(mx, __shfl_xor(mx, o));
        ma = fmaxf(ma, __shfl_xor(ma, o));
    }
    if ((threadIdx.x & 63) == 0) {
        atomicMax(&scal[0], enc_f(mx));  // max_sim
        atomicMax(&scal[1], enc_f(ma));  // max|X|
    }
}

// ---------- kernel B: init interleaved (dist, cross) float2 matrix ----------
__global__ void k_init(const float* __restrict__ X, const float* __restrict__ W,
                       float2* __restrict__ dc, const u32* __restrict__ scal) {
    int idx = blockIdx.x * blockDim.x + threadIdx.x;
    if (idx >= D * D) return;
    float max_sim = dec_f(scal[0]);
    float MAXD = __fmul_rn(dec_f(scal[1]), 1000.0f);
    int i = idx >> 10, j = idx & (D - 1);
    float x = X[idx];
    // X is bitwise symmetric (0.5*(A+A^T)), so this matches max_sim - X[min][max]
    float di = (i == j) ? MAXD : __fsub_rn(max_sim, x);
    float cx = (i == j) ? 0.0f : (W[idx] + W[j * D + i]);  // one addend is exactly 0
    dc[idx] = make_float2(di, cx);
}

// ---------- kernel B2: initial per-row (min,argmin) over upper triangle ----------
__global__ void k_rowmin(const float2* __restrict__ dc, float* __restrict__ values_g,
                         int* __restrict__ indices_g, const u32* __restrict__ scal) {
    int r = blockIdx.x;
    int lane = threadIdx.x;  // 64 threads = 1 wave
    float MAXD = __fmul_rn(dec_f(scal[1]), 1000.0f);
    u64 best = ((u64)__float_as_uint(MAXD) << 32);  // (MAXD, idx 0) like jnp.argmin on all-MAXD row
    const float4* row4 = (const float4*)(dc + (size_t)r * D);
    for (int c = lane; c < D / 2; c += 64) {
        float4 q = row4[c];
        int j0 = c << 1;
        if (j0 > r) {
            u64 k = ((u64)__float_as_uint(q.x) << 32) | (u32)j0;
            if (k < best) best = k;
        }
        if (j0 + 1 > r) {
            u64 k = ((u64)__float_as_uint(q.z) << 32) | (u32)(j0 + 1);
            if (k < best) best = k;
        }
    }
    for (int o = 32; o; o >>= 1) {
        u64 k2 = __shfl_xor(best, o);
        if (k2 < best) best = k2;
    }
    if (lane == 0) {
        values_g[r] = __uint_as_float((u32)(best >> 32));
        indices_g[r] = (int)(best & 0xffffffffu);
    }
}

// ---------- kernel C: persistent single-block HAC loop ----------
// Round-4 structure (best measured) + SPECULATIVE REGISTER LOADS:
// at the end of P3 every wave reads s_best[pb] (near-final: wave0/wave1 and
// most rescan publishes have landed) and loads its thread's element of both
// predicted rows into registers. Those loads drain at B3's vmcnt(0) together
// with the store drain (free). At P2, on a per-wave prediction hit
// (m1==rp && m2==ip, wave-uniform), the row data is ALREADY IN REGISTERS --
// zero memory latency on the serial chain. On miss: load as before (data
// fully drained at B3).
// Staleness (spec loads run while iter-k's row-m1/col-m1 stores are in
// flight) is fixed by the r7-proven LDS-history substitution, applied only
// on the hit path:
//   m == pm1  -> whole row from newv_h[pb]/crossv_h[pb]
//   t == pm1  -> single entry newv_h[pb][m] (symmetry: dc[m][pm1]==newv_prev[m])
// Misses read fresh memory (post-B3), no substitution needed.
__global__ void __launch_bounds__(1024) k_hac(
        float2* __restrict__ dc,
        const float* __restrict__ values_g, const int* __restrict__ indices_g,
        int* __restrict__ labels_g, const u32* __restrict__ scal) {
    __shared__ __align__(16) float values_l[D];
    __shared__ float values_stage[D];   // P3 scan results (restored next P2)
    __shared__ int indices_l[D];
    __shared__ __align__(16) float newv_h[2][D];    // cur/prev new dist row
    __shared__ __align__(16) float crossv_h[2][D];  // cur/prev new cross row
    __shared__ float cs_l[D];
    __shared__ unsigned char dead_l[D];
    __shared__ unsigned char marked_l[D];  // row staged in P3 -> restore next P2
    __shared__ int slot_l[D];   // leaf -> active slot id
    __shared__ int label_l[D];
    __shared__ double within_l[D];
    __shared__ double energy_l[D];
    __shared__ int rlist[2][D];
    __shared__ int nrec[2];
    __shared__ u64 s_best[2];   // double-buffered global-argmin accumulator
    __shared__ float s_cross12;
    __shared__ int s_takeP, s_m1P, s_labP;  // deferred cut (applied next iter)

    const int t = threadIdx.x;
    const int lane = t & 63, wid = t >> 6;
    const float MAXD = __fmul_rn(dec_f(scal[1]), 1000.0f);
    const u32 MAXDb = __float_as_uint(MAXD);

    values_l[t] = values_g[t];
    indices_l[t] = indices_g[t];
    cs_l[t] = 1.0f;
    dead_l[t] = 0;
    marked_l[t] = 0;
    slot_l[t] = t;
    label_l[t] = t;
    within_l[t] = 0.0;
    energy_l[t] = 0.0;
    if (t == 0) {
        s_takeP = 0; s_m1P = -1; s_labP = 0;
        nrec[0] = 0; nrec[1] = 0;
        s_best[0] = ~0ull; s_best[1] = ~0ull;
    }
    __syncthreads();
    // boot publish: per-wave reduce over own 64 rows -> atomicMin into s_best[0]
    {
        u64 key = ((u64)__float_as_uint(values_l[t]) << 32) | ((u32)t << 10) |
                  (u32)indices_l[t];
        for (int o = 32; o; o >>= 1) {
            u64 k2 = __shfl_xor(key, o);
            if (k2 < key) key = k2;
        }
        if (lane == 0) atomicMin(&s_best[0], key);
    }
    __syncthreads();

    // speculative-load state (live across B3)
    int rp_s = -1, ip_s = -1;
    float2 spec1 = make_float2(0.f, 0.f), spec2 = make_float2(0.f, 0.f);

    for (int it = 0; it < D - 1; ++it) {
        const int cb = it & 1, pb = cb ^ 1;

        // ================= P2 =================
        const u64 bk = s_best[cb];  // one LDS read -> m1 AND m2
        const int m1 = (int)((bk >> 10) & 1023);
        const int m2 = (int)(bk & 1023);

        // prediction check (wave-uniform). Hit: rows already in registers.
        const bool hit1 = (m1 == rp_s);
        const bool hit2 = (m2 == ip_s);
        float2 v1, v2;
        if (hit1) v1 = spec1; else v1 = dc[(size_t)m1 * D + t];
        if (hit2) v2 = spec2; else v2 = dc[(size_t)m2 * D + t];

        const float cs1 = cs_l[m1], cs2 = cs_l[m2];
        const float ncs = __fadd_rn(cs1, cs2);
        const int pm1 = s_m1P;
        const int takeP = s_takeP, labP = s_labP;
        if (t == 0) s_best[pb] = ~0ull;  // reset for this iter's publishers

        // restore staged P3 results, then freeze m2 (own-thread writes only)
        if (marked_l[t]) { values_l[t] = values_stage[t]; marked_l[t] = 0; }
        if (t == m2) {
            dead_l[m2] = 1;
            values_l[m2] = MAXD;  // vmask freeze
            indices_l[m2] = 0;    // argmin of all-MAXD row
        }
        const bool alive = !dead_l[t];

        float d1 = v1.x, c1 = v1.y, d2 = v2.x, c2 = v2.y;
        // staleness substitution on the HIT path only (spec loads ran while
        // iter-k's row/col-pm1 stores were in flight). Proven in r7.
        if (hit1) {
            if (m1 == pm1)     { d1 = newv_h[pb][t];  c1 = crossv_h[pb][t];  }
            else if (t == pm1) { d1 = newv_h[pb][m1]; c1 = crossv_h[pb][m1]; }
        }
        if (hit2) {
            if (m2 == pm1)     { d2 = newv_h[pb][t];  c2 = crossv_h[pb][t];  }
            else if (t == pm1) { d2 = newv_h[pb][m2]; c2 = crossv_h[pb][m2]; }
        }

        // deferred label apply (prev iter's cut), then slot merge
        {
            int sl = slot_l[t];
            if (takeP && sl == pm1) label_l[t] = labP;
            if (sl == m2) slot_l[t] = m1;
        }

        float nv = MAXD, ncx = 0.0f;
        bool do_st = false;
        if (t == m2) s_cross12 = c1;  // old cross(m1,m2), consumed post-B2
        if (alive && t != m1) {
            nv = __fdiv_rn(__fadd_rn(__fmul_rn(d1, cs1), __fmul_rn(d2, cs2)), ncs);
            ncx = c1 + c2;
            dc[(size_t)m1 * D + t] = make_float2(nv, ncx);  // row m1 (coalesced)
            do_st = true;                                   // col store deferred to P3
        }
        newv_h[cb][t] = nv;    // MAXD-fill: wave1 scan needs no dead mask
        crossv_h[cb][t] = ncx;

        // incremental row-min maintenance (thread t == row t)
        {
            float v = values_l[t];
            if (t == m1) {
                values_l[t] = MAXD;  // transient; wave1 stages the new min
                marked_l[t] = 1;
            } else if (alive && v < MAXD) {
                int idx = indices_l[t];
                if (idx == m2) {
                    rlist[cb][atomicAdd(&nrec[cb], 1)] = t;
                    values_l[t] = MAXD;
                    marked_l[t] = 1;
                } else if (idx == m1) {  // implies t < m1
                    if (nv <= v) values_l[t] = nv;  // lowest-index tie preserved
                    else {
                        rlist[cb][atomicAdd(&nrec[cb], 1)] = t;
                        values_l[t] = MAXD;
                        marked_l[t] = 1;
                    }
                } else if (t < m1) {  // col m1 got nv in row t
                    if (nv < v) { values_l[t] = nv; indices_l[t] = m1; }
                    else if (nv == v && m1 < idx) indices_l[t] = m1;  // jnp.argmin tie-break
                }
            }
        }
        barrier_lds_only();  // B2: LDS-only; row-m1 store drains under P3

        // ================= P3 =================
        if (t == m1) cs_l[m1] = ncs;  // nobody reads cs_l[m1] in P3
        const int n = nrec[cb];
        if (t == 0) nrec[pb] = 0;

        if (wid == 0) {
            // col store early: wave0's scan is LDS-only, store drains under it
            if (do_st) dc[(size_t)t * D + m1] = make_float2(nv, ncx);
            if (lane == 0) {
                // cut decision (f64 accumulators)
                double merge_e = within_l[m1] + within_l[m2] + (double)s_cross12;
                double e_sum = energy_l[m1] + energy_l[m2];
                int take = (merge_e >= e_sum) ? 1 : 0;
                within_l[m1] = merge_e;
                energy_l[m1] = take ? merge_e : e_sum;
                s_takeP = take;
                s_m1P = m1;
                s_labP = D + it;
            }
            // full argmin scan of values_l (marked rows are MAXD and stable;
            // their true keys come from wave1/rescan publishers)
            const float4* v4 = (const float4*)values_l;
            u64 bb = ~0ull;  // (val<<32)|row during reduce
#pragma unroll
            for (int c = 0; c < 4; ++c) {
                int fi = lane + 64 * c;
                float4 q = v4[fi];
                int b = fi << 2;
                u64 k;
                k = ((u64)__float_as_uint(q.x) << 32) | (u32)(b + 0); if (k < bb) bb = k;
                k = ((u64)__float_as_uint(q.y) << 32) | (u32)(b + 1); if (k < bb) bb = k;
                k = ((u64)__float_as_uint(q.z) << 32) | (u32)(b + 2); if (k < bb) bb = k;
                k = ((u64)__float_as_uint(q.w) << 32) | (u32)(b + 3); if (k < bb) bb = k;
            }
            for (int o = 32; o; o >>= 1) {
                u64 k2 = __shfl_xor(bb, o);
                if (k2 < bb) bb = k2;
            }
            if (lane == 0) {
                int r = (int)(bb & 1023);
                int idx = indices_l[r];  // r is unmarked -> stable during P3
                atomicMin(&s_best[pb],
                          (bb & 0xffffffff00000000ull) | ((u32)r << 10) | (u32)idx);
            }
        } else if (wid == 1) {
            // col store early: wave1's scan is LDS-only, store drains under it
            if (do_st) dc[(size_t)t * D + m1] = make_float2(nv, ncx);
            // row m1's new min from LDS newv_h (dead cols are MAXD by construction)
            u64 bb = ((u64)MAXDb << 32);  // (val<<32)|col
            const float4* nv4 = (const float4*)newv_h[cb];
            for (int c = lane; c < D / 4; c += 64) {
                float4 q = nv4[c];
                int j0 = c << 2;
#pragma unroll
                for (int e = 0; e < 4; ++e) {
                    int j = j0 + e;
                    float dv = (e == 0) ? q.x : (e == 1) ? q.y : (e == 2) ? q.z : q.w;
                    if (j > m1) {
                        u64 k = ((u64)__float_as_uint(dv) << 32) | (u32)j;
                        if (k < bb) bb = k;
                    }
                }
            }
            for (int o = 32; o; o >>= 1) {
                u64 k2 = __shfl_xor(bb, o);
                if (k2 < bb) bb = k2;
            }
            if (lane == 0) {
                values_stage[m1] = __uint_as_float((u32)(bb >> 32));
                indices_l[m1] = (int)(bb & 0xffffffffu);
                atomicMin(&s_best[pb],
                          (bb & 0xffffffff00000000ull) | ((u32)m1 << 10) | (bb & 1023));
            }
        } else {
            // residual rescans (argmin retired/rose), one wave per row.
            // Row loads issue BEFORE the col store: in-order vmcnt means a
            // store-first ordering would stall load consumption on the
            // scattered store's RFO latency.
            bool pend_st = do_st;
            for (int q = wid - 2; q < n; q += 14) {
                const int r = rlist[cb][q];
                const float subst = newv_h[cb][r];  // col-m1 value (store in flight)
                const float4* row4 = (const float4*)(dc + (size_t)r * D);
                float4 a0 = row4[lane];
                float4 a1 = row4[lane + 64];
                float4 a2 = row4[lane + 128];
                float4 a3 = row4[lane + 192];
                float4 a4 = row4[lane + 256];
                float4 a5 = row4[lane + 320];
                float4 a6 = row4[lane + 384];
                float4 a7 = row4[lane + 448];
                if (pend_st) {  // issue after loads; drains under the reduce
                    dc[(size_t)t * D + m1] = make_float2(nv, ncx);
                    pend_st = false;
                }
                u64 bb = ((u64)MAXDb << 32);  // (val<<32)|col
#define ACC2(af, koff)                                                          \
                {                                                               \
                    int j0 = (lane + (koff)) << 1;                              \
                    float dv0 = (j0 == m1) ? subst : (af).x;                    \
                    if (j0 > r && !dead_l[j0]) {                                \
                        u64 k = ((u64)__float_as_uint(dv0) << 32) | (u32)j0;    \
                        if (k < bb) bb = k;                                     \
                    }                                                           \
                    int j1 = j0 + 1;                                            \
                    float dv1 = (j1 == m1) ? subst : (af).z;                    \
                    if (j1 > r && !dead_l[j1]) {                                \
                        u64 k = ((u64)__float_as_uint(dv1) << 32) | (u32)j1;    \
                        if (k < bb) bb = k;                                     \
                    }                                                           \
                }
                ACC2(a0, 0)
                ACC2(a1, 64)
                ACC2(a2, 128)
                ACC2(a3, 192)
                ACC2(a4, 256)
                ACC2(a5, 320)
                ACC2(a6, 384)
                ACC2(a7, 448)
#undef ACC2
                for (int o = 32; o; o >>= 1) {
                    u64 k2 = __shfl_xor(bb, o);
                    if (k2 < bb) bb = k2;
                }
                if (lane == 0) {
                    values_stage[r] = __uint_as_float((u32)(bb >> 32));
                    indices_l[r] = (int)(bb & 0xffffffffu);
                    atomicMin(&s_best[pb],
                              (bb & 0xffffffff00000000ull) | ((u32)r << 10) | (bb & 1023));
                }
            }
            if (pend_st) dc[(size_t)t * D + m1] = make_float2(nv, ncx);
        }

        // ---- speculative register loads for the next iteration (all waves).
        // s_best[pb] is near-final here (wave0/wave1 + most rescan publishes
        // landed). A late atomicMin after this read just causes a miss.
        // Loads drain at B3's vmcnt(0) together with the store drain.
        {
            const u64 pred = s_best[pb];
            rp_s = (int)((pred >> 10) & 1023);
            ip_s = (int)(pred & 1023);
            spec1 = dc[(size_t)rp_s * D + t];
            spec2 = dc[(size_t)ip_s * D + t];
        }
        __syncthreads();  // B3: full drain; stores AND spec loads retire here
    }

    // apply the final iteration's deferred cut, then emit labels
    {
        int lab = label_l[t];
        if (s_takeP && slot_l[t] == s_m1P) lab = s_labP;
        labels_g[t] = lab;
    }
}

// ---------- kernel D: R[a][b] = (a==b) || (label[a]==label[b]) ----------
__global__ void k_out(const int* __restrict__ labels, float* __restrict__ out) {
    int idx = blockIdx.x * blockDim.x + threadIdx.x;
    if (idx >= D * D) return;
    int i = idx >> 10, j = idx & (D - 1);
    out[idx] = (i == j || labels[i] == labels[j]) ? 1.0f : 0.0f;
}

extern "C" void kernel_launch(void* const* d_in, const int* in_sizes, int n_in,
                              void* d_out, int out_size, void* d_ws, size_t ws_size,
                              hipStream_t stream) {
    const float* X = (const float*)d_in[0];
    const float* W = (const float*)d_in[1];

    char* ws = (char*)d_ws;
    const size_t MAT_BYTES = (size_t)D * D * sizeof(float);  // 4 MiB
    float2* dc = (float2*)ws;                                // 8 MiB interleaved
    float* values_g = (float*)(ws + 2 * MAT_BYTES);
    int* indices_g = (int*)(ws + 2 * MAT_BYTES + 4096);
    int* labels_g = (int*)(ws + 2 * MAT_BYTES + 8192);
    u32* scal = (u32*)(ws + 2 * MAT_BYTES + 12288);

    hipMemsetAsync(scal, 0, 2 * sizeof(u32), stream);
    k_maxred<<<256, 256, 0, stream>>>(X, scal);
    k_init<<<(D * D) / 256, 256, 0, stream>>>(X, W, dc, scal);
    k_rowmin<<<D, 64, 0, stream>>>(dc, values_g, indices_g, scal);
    k_hac<<<1, 1024, 0, stream>>>(dc, values_g, indices_g, labels_g, scal);
    k_out<<<(D * D) / 256, 256, 0, stream>>>(labels_g, (float*)d_out);
}

// Round 13
// 3020.815 us; speedup vs baseline: 1.0874x; 1.0874x over previous
//
#include <hip/hip_runtime.h>
#include <stdint.h>

#define D 1024

typedef unsigned long long u64;
typedef unsigned int u32;

// ---------- monotonic float<->uint mapping for atomic max ----------
__device__ __forceinline__ u32 enc_f(float f) {
    u32 b = __float_as_uint(f);
    return (b & 0x80000000u) ? ~b : (b | 0x80000000u);
}
__device__ __forceinline__ float dec_f(u32 u) {
    u32 b = (u & 0x80000000u) ? (u ^ 0x80000000u) : ~u;
    return __uint_as_float(b);
}

// LDS-only barrier: synchronizes DS traffic but does NOT drain vmcnt.
// Used at B2 only: the sole pending global store there is the coalesced
// row-m1 store, which has NO consumer inside P3 (rescans substitute col m1
// from LDS and never read row m1; wave0/wave1 scan LDS only). It drains
// in the shadow of P3 and is retired by the full __syncthreads() at B3.
__device__ __forceinline__ void barrier_lds_only() {
    __builtin_amdgcn_sched_barrier(0);
    asm volatile("s_waitcnt lgkmcnt(0)" ::: "memory");
    __builtin_amdgcn_s_barrier();
    asm volatile("" ::: "memory");
    __builtin_amdgcn_sched_barrier(0);
}

// ---------- kernel A: max(X), max|X| ----------
__global__ void k_maxred(const float* __restrict__ X, u32* scal) {
    float mx = -INFINITY, ma = 0.f;
    int stride = gridDim.x * blockDim.x;
    for (int i = blockIdx.x * blockDim.x + threadIdx.x; i < D * D; i += stride) {
        float v = X[i];
        mx = fmaxf(mx, v);
        ma = fmaxf(ma, fabsf(v));
    }
    for (int o = 32; o; o >>= 1) {
        mx = fmaxf(mx, __shfl_xor(mx, o));
        ma = fmaxf(ma, __shfl_xor(ma, o));
    }
    if ((threadIdx.x & 63) == 0) {
        atomicMax(&scal[0], enc_f(mx));  // max_sim
        atomicMax(&scal[1], enc_f(ma));  // max|X|
    }
}

// ---------- kernel B: init interleaved (dist, cross) float2 matrix ----------
__global__ void k_init(const float* __restrict__ X, const float* __restrict__ W,
                       float2* __restrict__ dc, const u32* __restrict__ scal) {
    int idx = blockIdx.x * blockDim.x + threadIdx.x;
    if (idx >= D * D) return;
    float max_sim = dec_f(scal[0]);
    float MAXD = __fmul_rn(dec_f(scal[1]), 1000.0f);
    int i = idx >> 10, j = idx & (D - 1);
    float x = X[idx];
    // X is bitwise symmetric (0.5*(A+A^T)), so this matches max_sim - X[min][max]
    float di = (i == j) ? MAXD : __fsub_rn(max_sim, x);
    float cx = (i == j) ? 0.0f : (W[idx] + W[j * D + i]);  // one addend is exactly 0
    dc[idx] = make_float2(di, cx);
}

// ---------- kernel B2: initial per-row (min,argmin) over upper triangle ----------
__global__ void k_rowmin(const float2* __restrict__ dc, float* __restrict__ values_g,
                         int* __restrict__ indices_g, const u32* __restrict__ scal) {
    int r = blockIdx.x;
    int lane = threadIdx.x;  // 64 threads = 1 wave
    float MAXD = __fmul_rn(dec_f(scal[1]), 1000.0f);
    u64 best = ((u64)__float_as_uint(MAXD) << 32);  // (MAXD, idx 0) like jnp.argmin on all-MAXD row
    const float4* row4 = (const float4*)(dc + (size_t)r * D);
    for (int c = lane; c < D / 2; c += 64) {
        float4 q = row4[c];
        int j0 = c << 1;
        if (j0 > r) {
            u64 k = ((u64)__float_as_uint(q.x) << 32) | (u32)j0;
            if (k < best) best = k;
        }
        if (j0 + 1 > r) {
            u64 k = ((u64)__float_as_uint(q.z) << 32) | (u32)(j0 + 1);
            if (k < best) best = k;
        }
    }
    for (int o = 32; o; o >>= 1) {
        u64 k2 = __shfl_xor(best, o);
        if (k2 < best) best = k2;
    }
    if (lane == 0) {
        values_g[r] = __uint_as_float((u32)(best >> 32));
        indices_g[r] = (int)(best & 0xffffffffu);
    }
}

// ---------- kernel C: persistent single-block HAC loop (round-4 optimum) ----------
// Structural constraints established by 13 measured experiments:
//  * scattered symmetric-mirror col store (1024 RFO lines/iter) is required
//    for coalesced row reads; gather-later schemes move the scatter onto
//    P2's serial chain (worse).
//  * the scatter must drain at a LOAD-FREE full barrier (B3): overlapping it
//    with any load traffic -- same wave (r1), other waves (r7), spec loads
//    (r12) -- costs more than the drain.
//  * P2's serial chain (s_best decode -> row loads -> maintenance -> B2) is
//    the critical path; any work added there (r9, r10) regresses; P3's scans
//    are hidden under rescans + drain (r9).
//  * B2 needs no vmcnt drain (row-m1 store has no P3 consumer).
//  * early unconditional row loads + wave0 candidate prefetch are the only
//    P2-latency reducers that paid off (r4: -133 us).
__global__ void __launch_bounds__(1024) k_hac(
        float2* __restrict__ dc,
        const float* __restrict__ values_g, const int* __restrict__ indices_g,
        int* __restrict__ labels_g, const u32* __restrict__ scal) {
    __shared__ __align__(16) float values_l[D];
    __shared__ float values_stage[D];   // P3 scan results (restored next P2)
    __shared__ int indices_l[D];
    __shared__ __align__(16) float newv_l[D];
    __shared__ float cs_l[D];
    __shared__ unsigned char dead_l[D];
    __shared__ unsigned char marked_l[D];  // row staged in P3 -> restore next P2
    __shared__ int slot_l[D];   // leaf -> active slot id
    __shared__ int label_l[D];
    __shared__ double within_l[D];
    __shared__ double energy_l[D];
    __shared__ int rlist[2][D];
    __shared__ int nrec[2];
    __shared__ u64 s_best[2];   // double-buffered global-argmin accumulator
    __shared__ float s_cross12;
    __shared__ int s_takeP, s_m1P, s_labP;  // deferred cut (applied next iter)

    const int t = threadIdx.x;
    const int lane = t & 63, wid = t >> 6;
    const float MAXD = __fmul_rn(dec_f(scal[1]), 1000.0f);
    const u32 MAXDb = __float_as_uint(MAXD);

    values_l[t] = values_g[t];
    indices_l[t] = indices_g[t];
    cs_l[t] = 1.0f;
    dead_l[t] = 0;
    marked_l[t] = 0;
    slot_l[t] = t;
    label_l[t] = t;
    within_l[t] = 0.0;
    energy_l[t] = 0.0;
    if (t == 0) {
        s_takeP = 0; s_m1P = -1; s_labP = 0;
        nrec[0] = 0; nrec[1] = 0;
        s_best[0] = ~0ull; s_best[1] = ~0ull;
    }
    __syncthreads();
    // boot publish: per-wave reduce over own 64 rows -> atomicMin into s_best[0]
    {
        u64 key = ((u64)__float_as_uint(values_l[t]) << 32) | ((u32)t << 10) |
                  (u32)indices_l[t];
        for (int o = 32; o; o >>= 1) {
            u64 k2 = __shfl_xor(key, o);
            if (k2 < key) key = k2;
        }
        if (lane == 0) atomicMin(&s_best[0], key);
    }
    __syncthreads();

    float pf0 = 0.f, pf1 = 0.f, pf2 = 0.f, pf3 = 0.f;  // prefetch sinks

    for (int it = 0; it < D - 1; ++it) {
        const int cb = it & 1, pb = cb ^ 1;

        // ================= P2 =================
        const u64 bk = s_best[cb];  // one LDS read -> m1 AND m2
        const int m1 = (int)((bk >> 10) & 1023);
        const int m2 = (int)(bk & 1023);

        // row loads FIRST: unconditional, no LDS dependency beyond s_best.
        // (Likely L1/L2 hits when wave0's prefetch predicted correctly.)
        const float2 v1 = dc[(size_t)m1 * D + t];
        const float2 v2 = dc[(size_t)m2 * D + t];

        const float cs1 = cs_l[m1], cs2 = cs_l[m2];
        const float ncs = __fadd_rn(cs1, cs2);
        const int pm1 = s_m1P;
        const int takeP = s_takeP, labP = s_labP;
        if (t == 0) s_best[pb] = ~0ull;  // reset for this iter's publishers

        // restore staged P3 results, then freeze m2 (own-thread writes only)
        if (marked_l[t]) { values_l[t] = values_stage[t]; marked_l[t] = 0; }
        if (t == m2) {
            dead_l[m2] = 1;
            values_l[m2] = MAXD;  // vmask freeze
            indices_l[m2] = 0;    // argmin of all-MAXD row
        }
        const bool alive = !dead_l[t];

        const float d1 = v1.x, c1 = v1.y, d2 = v2.x, c2 = v2.y;

        // deferred label apply (prev iter's cut), then slot merge
        {
            int sl = slot_l[t];
            if (takeP && sl == pm1) label_l[t] = labP;
            if (sl == m2) slot_l[t] = m1;
        }

        float nv = MAXD, ncx = 0.0f;
        bool do_st = false;
        if (t == m2) s_cross12 = c1;  // old cross(m1,m2), consumed post-B2
        if (alive && t != m1) {
            nv = __fdiv_rn(__fadd_rn(__fmul_rn(d1, cs1), __fmul_rn(d2, cs2)), ncs);
            ncx = c1 + c2;
            dc[(size_t)m1 * D + t] = make_float2(nv, ncx);  // row m1 (coalesced)
            do_st = true;                                   // col store deferred to P3
        }
        newv_l[t] = nv;  // MAXD-fill: wave1 scan needs no dead mask

        // incremental row-min maintenance (thread t == row t)
        {
            float v = values_l[t];
            if (t == m1) {
                values_l[t] = MAXD;  // transient; wave1 stages the new min
                marked_l[t] = 1;
            } else if (alive && v < MAXD) {
                int idx = indices_l[t];
                if (idx == m2) {
                    rlist[cb][atomicAdd(&nrec[cb], 1)] = t;
                    values_l[t] = MAXD;
                    marked_l[t] = 1;
                } else if (idx == m1) {  // implies t < m1
                    if (nv <= v) values_l[t] = nv;  // lowest-index tie preserved
                    else {
                        rlist[cb][atomicAdd(&nrec[cb], 1)] = t;
                        values_l[t] = MAXD;
                        marked_l[t] = 1;
                    }
                } else if (t < m1) {  // col m1 got nv in row t
                    if (nv < v) { values_l[t] = nv; indices_l[t] = m1; }
                    else if (nv == v && m1 < idx) indices_l[t] = m1;  // jnp.argmin tie-break
                }
            }
        }
        barrier_lds_only();  // B2: LDS-only; row-m1 store drains under P3

        // ================= P3 =================
        if (t == m1) cs_l[m1] = ncs;  // nobody reads cs_l[m1] in P3
        const int n = nrec[cb];
        if (t == 0) nrec[pb] = 0;

        if (wid == 0) {
            // col store early: wave0's scan is LDS-only, store drains under it
            if (do_st) dc[(size_t)t * D + m1] = make_float2(nv, ncx);
            if (lane == 0) {
                // cut decision (f64 accumulators)
                double merge_e = within_l[m1] + within_l[m2] + (double)s_cross12;
                double e_sum = energy_l[m1] + energy_l[m2];
                int take = (merge_e >= e_sum) ? 1 : 0;
                within_l[m1] = merge_e;
                energy_l[m1] = take ? merge_e : e_sum;
                s_takeP = take;
                s_m1P = m1;
                s_labP = D + it;
            }
            // full argmin scan of values_l (marked rows are MAXD and stable;
            // their true keys come from wave1/rescan publishers)
            const float4* v4 = (const float4*)values_l;
            u64 bb = ~0ull;  // (val<<32)|row during reduce
#pragma unroll
            for (int c = 0; c < 4; ++c) {
                int fi = lane + 64 * c;
                float4 q = v4[fi];
                int b = fi << 2;
                u64 k;
                k = ((u64)__float_as_uint(q.x) << 32) | (u32)(b + 0); if (k < bb) bb = k;
                k = ((u64)__float_as_uint(q.y) << 32) | (u32)(b + 1); if (k < bb) bb = k;
                k = ((u64)__float_as_uint(q.z) << 32) | (u32)(b + 2); if (k < bb) bb = k;
                k = ((u64)__float_as_uint(q.w) << 32) | (u32)(b + 3); if (k < bb) bb = k;
            }
            for (int o = 32; o; o >>= 1) {
                u64 k2 = __shfl_xor(bb, o);
                if (k2 < bb) bb = k2;
            }
            if (lane == 0) {
                int r = (int)(bb & 1023);
                int idx = indices_l[r];  // r is unmarked -> stable during P3
                atomicMin(&s_best[pb],
                          (bb & 0xffffffff00000000ull) | ((u32)r << 10) | (u32)idx);
            }
            // speculative prefetch of the candidate pair's rows (likely next
            // m1/m2). One dword per 64B segment covers every cache line of
            // both 8KB rows. Values consumed by the asm sink after B3, where
            // vmcnt is already 0 -> zero added wait.
            {
                int r_pf = (int)(bb & 1023);
                int i_pf = indices_l[r_pf];
                const float* br = (const float*)(dc + (size_t)r_pf * D);
                const float* bi = (const float*)(dc + (size_t)i_pf * D);
                pf0 = br[lane * 16];
                pf1 = br[1024 + lane * 16];
                pf2 = bi[lane * 16];
                pf3 = bi[1024 + lane * 16];
            }
        } else if (wid == 1) {
            // col store early: wave1's scan is LDS-only, store drains under it
            if (do_st) dc[(size_t)t * D + m1] = make_float2(nv, ncx);
            // row m1's new min from LDS newv_l (dead cols are MAXD by construction)
            u64 bb = ((u64)MAXDb << 32);  // (val<<32)|col
            const float4* nv4 = (const float4*)newv_l;
            for (int c = lane; c < D / 4; c += 64) {
                float4 q = nv4[c];
                int j0 = c << 2;
#pragma unroll
                for (int e = 0; e < 4; ++e) {
                    int j = j0 + e;
                    float dv = (e == 0) ? q.x : (e == 1) ? q.y : (e == 2) ? q.z : q.w;
                    if (j > m1) {
                        u64 k = ((u64)__float_as_uint(dv) << 32) | (u32)j;
                        if (k < bb) bb = k;
                    }
                }
            }
            for (int o = 32; o; o >>= 1) {
                u64 k2 = __shfl_xor(bb, o);
                if (k2 < bb) bb = k2;
            }
            if (lane == 0) {
                values_stage[m1] = __uint_as_float((u32)(bb >> 32));
                indices_l[m1] = (int)(bb & 0xffffffffu);
                atomicMin(&s_best[pb],
                          (bb & 0xffffffff00000000ull) | ((u32)m1 << 10) | (bb & 1023));
            }
        } else {
            // residual rescans (argmin retired/rose), one wave per row.
            // Row loads issue BEFORE the col store: in-order vmcnt means a
            // store-first ordering would stall load consumption on the
            // scattered store's RFO latency.
            bool pend_st = do_st;
            for (int q = wid - 2; q < n; q += 14) {
                const int r = rlist[cb][q];
                const float subst = newv_l[r];  // col-m1 value (store in flight)
                const float4* row4 = (const float4*)(dc + (size_t)r * D);
                float4 a0 = row4[lane];
                float4 a1 = row4[lane + 64];
                float4 a2 = row4[lane + 128];
                float4 a3 = row4[lane + 192];
                float4 a4 = row4[lane + 256];
                float4 a5 = row4[lane + 320];
                float4 a6 = row4[lane + 384];
                float4 a7 = row4[lane + 448];
                if (pend_st) {  // issue after loads; drains under the reduce
                    dc[(size_t)t * D + m1] = make_float2(nv, ncx);
                    pend_st = false;
                }
                u64 bb = ((u64)MAXDb << 32);  // (val<<32)|col
#define ACC2(af, koff)                                                          \
                {                                                               \
                    int j0 = (lane + (koff)) << 1;                              \
                    float dv0 = (j0 == m1) ? subst : (af).x;                    \
                    if (j0 > r && !dead_l[j0]) {                                \
                        u64 k = ((u64)__float_as_uint(dv0) << 32) | (u32)j0;    \
                        if (k < bb) bb = k;                                     \
                    }                                                           \
                    int j1 = j0 + 1;                                            \
                    float dv1 = (j1 == m1) ? subst : (af).z;                    \
                    if (j1 > r && !dead_l[j1]) {                                \
                        u64 k = ((u64)__float_as_uint(dv1) << 32) | (u32)j1;    \
                        if (k < bb) bb = k;                                     \
                    }                                                           \
                }
                ACC2(a0, 0)
                ACC2(a1, 64)
                ACC2(a2, 128)
                ACC2(a3, 192)
                ACC2(a4, 256)
                ACC2(a5, 320)
                ACC2(a6, 384)
                ACC2(a7, 448)
#undef ACC2
                for (int o = 32; o; o >>= 1) {
                    u64 k2 = __shfl_xor(bb, o);
                    if (k2 < bb) bb = k2;
                }
                if (lane == 0) {
                    values_stage[r] = __uint_as_float((u32)(bb >> 32));
                    indices_l[r] = (int)(bb & 0xffffffffu);
                    atomicMin(&s_best[pb],
                              (bb & 0xffffffff00000000ull) | ((u32)r << 10) | (bb & 1023));
                }
            }
            if (pend_st) dc[(size_t)t * D + m1] = make_float2(nv, ncx);
        }
        __syncthreads();  // B3: full drain; all waves' stores retire in parallel
        // keep the prefetch loads alive; vmcnt already 0 here -> free
        if (wid == 0) asm volatile("" :: "v"(pf0), "v"(pf1), "v"(pf2), "v"(pf3));
    }

    // apply the final iteration's deferred cut, then emit labels
    {
        int lab = label_l[t];
        if (s_takeP && slot_l[t] == s_m1P) lab = s_labP;
        labels_g[t] = lab;
    }
}

// ---------- kernel D: R[a][b] = (a==b) || (label[a]==label[b]) ----------
__global__ void k_out(const int* __restrict__ labels, float* __restrict__ out) {
    int idx = blockIdx.x * blockDim.x + threadIdx.x;
    if (idx >= D * D) return;
    int i = idx >> 10, j = idx & (D - 1);
    out[idx] = (i == j || labels[i] == labels[j]) ? 1.0f : 0.0f;
}

extern "C" void kernel_launch(void* const* d_in, const int* in_sizes, int n_in,
                              void* d_out, int out_size, void* d_ws, size_t ws_size,
                              hipStream_t stream) {
    const float* X = (const float*)d_in[0];
    const float* W = (const float*)d_in[1];

    char* ws = (char*)d_ws;
    const size_t MAT_BYTES = (size_t)D * D * sizeof(float);  // 4 MiB
    float2* dc = (float2*)ws;                                // 8 MiB interleaved
    float* values_g = (float*)(ws + 2 * MAT_BYTES);
    int* indices_g = (int*)(ws + 2 * MAT_BYTES + 4096);
    int* labels_g = (int*)(ws + 2 * MAT_BYTES + 8192);
    u32* scal = (u32*)(ws + 2 * MAT_BYTES + 12288);

    hipMemsetAsync(scal, 0, 2 * sizeof(u32), stream);
    k_maxred<<<256, 256, 0, stream>>>(X, scal);
    k_init<<<(D * D) / 256, 256, 0, stream>>>(X, W, dc, scal);
    k_rowmin<<<D, 64, 0, stream>>>(dc, values_g, indices_g, scal);
    k_hac<<<1, 1024, 0, stream>>>(dc, values_g, indices_g, labels_g, scal);
    k_out<<<(D * D) / 256, 256, 0, stream>>>(labels_g, (float*)d_out);
}